// Round 3
// baseline (426.279 us; speedup 1.0000x reference)
//
#include <hip/hip_runtime.h>
#include <math.h>

namespace {
constexpr int Kc = 1024;   // num_embeddings
constexpr int Dd = 64;     // embedding_dim

// numpy pairwise_sum of squares, n=64, exact numpy op order:
//   tmp[d] = fl(a[d]*a[d]) elementwise (rounded BEFORE summing -> contract off)
//   r[j]=tmp[j]; for i=8..56 step 8: r[j]+=tmp[i+j];
//   res = ((r0+r1)+(r2+r3)) + ((r4+r5)+(r6+r7))
__device__ inline float np_sumsq64(const float* __restrict__ a) {
#pragma clang fp contract(off)
    float r[8];
    #pragma unroll
    for (int j = 0; j < 8; ++j) r[j] = a[j] * a[j];
    #pragma unroll
    for (int i = 8; i < 64; i += 8) {
        #pragma unroll
        for (int j = 0; j < 8; ++j) {
            float s = a[i + j] * a[i + j];   // rounded square
            r[j] = r[j] + s;                 // no FMA fusion (contract off)
        }
    }
    return ((r[0] + r[1]) + (r[2] + r[3])) + ((r[4] + r[5]) + (r[6] + r[7]));
}

// ---- precompute ee[k] = np.sum(emb*emb, axis=1) bitwise (pairwise order) ----
__global__ void k_ee(const float* __restrict__ emb, float* __restrict__ ee) {
    int k = blockIdx.x * blockDim.x + threadIdx.x;
    ee[k] = np_sumsq64(emb + (size_t)k * Dd);
}

// ---- main: 1024 blocks x 256 thr; 64 pixels/block, 4 wave-uniform k-pieces ----
__global__ __launch_bounds__(256, 4) void k_main(
    const float* __restrict__ inputs, const float* __restrict__ emb,
    const float* __restrict__ ee_g, float* __restrict__ quant,
    float* __restrict__ enc, float* __restrict__ idx_out,
    unsigned int* __restrict__ hist, float* __restrict__ partials)
{
    __shared__ float sb[4][64];
    __shared__ int   si[4][64];

    const int tid = threadIdx.x;
    const int p = __builtin_amdgcn_readfirstlane(tid >> 6);  // wave-uniform piece
    const int l = tid & 63;                                  // pixel within block
    const int n = blockIdx.x * 64 + l;
    const int b = n >> 10;
    const int hw = n & 1023;

    // x[d] = inputs[b, d, h, w]  (coalesced across the wave for each d)
    const float* xin = inputs + (size_t)b * (Dd * 1024) + hw;
    float x[Dd];
    #pragma unroll
    for (int d = 0; d < Dd; ++d) x[d] = xin[d * 1024];

    const float xx = np_sumsq64(x);   // numpy-order fp32 ||x||^2

    // block zeroes its own 64 encoding rows (16384 float4), hidden under FMAs
    float4* enc4 = (float4*)enc + (size_t)blockIdx.x * 16384 + tid;

    float best = INFINITY;
    int i1 = 0;
    const int k0 = p * 256;
    for (int kk = 0; kk < 256; ++kk) {
        const int k = __builtin_amdgcn_readfirstlane(k0 + kk);  // force uniform -> s_load
        const float* ek = emb + (size_t)k * Dd;
        // sgemm emulation: sequential fp32 FMA over d (single accumulator)
        float g = 0.f;
        #pragma unroll
        for (int d = 0; d < Dd; ++d) g = fmaf(x[d], ek[d], g);
        // numpy: dist = fl( fl(xx + ee[k]) - 2*g )   (x2 exact; one rounding each)
        float A = xx + ee_g[k];
        float dist = fmaf(-2.f, g, A);
        bool lt = dist < best;            // strict < : first-index tie-break
        best = lt ? dist : best;
        i1   = lt ? k    : i1;
        if ((kk & 3) == 0) {              // 256 KB zero-fill interleaved
            *enc4 = float4{0.f, 0.f, 0.f, 0.f};
            enc4 += 256;
        }
    }

    sb[p][l] = best; si[p][l] = i1;
    __syncthreads();   // also drains this block's enc zero-fill stores

    if (tid < 64) {    // wave 0: merge 4 pieces; ascending piece order keeps
                       // global first-index tie-break (piece q's ks < piece q+1's)
        best = INFINITY; i1 = 0;
        #pragma unroll
        for (int q = 0; q < 4; ++q) {
            float s = sb[q][l];
            int   i = si[q][l];
            bool lt = s < best;
            best = lt ? s : best;
            i1   = lt ? i : i1;
        }

        // quantized output: gather codebook row, store NCHW (coalesced per d)
        {
            const float4* eb = (const float4*)(emb + (size_t)i1 * Dd);
            float* qout = quant + (size_t)b * (Dd * 1024) + hw;
            #pragma unroll
            for (int i = 0; i < Dd / 4; ++i) {
                float4 v = eb[i];
                qout[(i * 4 + 0) * 1024] = v.x;
                qout[(i * 4 + 1) * 1024] = v.y;
                qout[(i * 4 + 2) * 1024] = v.z;
                qout[(i * 4 + 3) * 1024] = v.w;
            }
        }

        idx_out[n] = (float)i1;
        atomicAdd(hist + i1, 1u);

        // one-hot scatter into this block's own (already-zeroed) rows
        enc[(size_t)n * Kc + i1] = 1.0f;

        // loss partial: dist_min == ||x - e*||^2 (includes ||x||^2 already)
        float v = best;
        #pragma unroll
        for (int off = 32; off > 0; off >>= 1) v += __shfl_down(v, off, 64);
        if (l == 0) partials[blockIdx.x] = v;
    }
}

// ---- final: perplexity from histogram, loss from partials ----
__global__ __launch_bounds__(1024) void k_fin(
    const unsigned int* __restrict__ hist, const float* __restrict__ partials,
    float* __restrict__ loss_out, float* __restrict__ perp_out)
{
    __shared__ double sd[1024];
    int tid = threadIdx.x;
    double p = (double)hist[tid] * (1.0 / 65536.0);
    sd[tid] = p * log(p + 1e-10);
    __syncthreads();
    for (int s = 512; s > 0; s >>= 1) {
        if (tid < s) sd[tid] += sd[tid + s];
        __syncthreads();
    }
    double ent = sd[0];
    __syncthreads();
    sd[tid] = (double)partials[tid];
    __syncthreads();
    for (int s = 512; s > 0; s >>= 1) {
        if (tid < s) sd[tid] += sd[tid + s];
        __syncthreads();
    }
    if (tid == 0) {
        double perp = exp(-ent);
        double mean = sd[0] * (1.0 / 4194304.0);   // sum ||x-e||^2 / (N*D)
        double loss = 1.25 * mean + 0.1 * (1024.0 - perp) / 1024.0;
        loss_out[0] = (float)loss;
        perp_out[0] = (float)perp;
    }
}
} // namespace

extern "C" void kernel_launch(void* const* d_in, const int* in_sizes, int n_in,
                              void* d_out, int out_size, void* d_ws, size_t ws_size,
                              hipStream_t stream)
{
    const float* inputs = (const float*)d_in[0];   // [64,64,32,32] fp32
    const float* emb    = (const float*)d_in[1];   // [1024,64] fp32
    float* out = (float*)d_out;

    float* loss_out = out;                            // [1]
    float* quant    = out + 1;                        // [64,64,32,32]
    float* perp_out = out + 1 + 4194304;              // [1]
    float* enc      = out + 2 + 4194304;              // [65536,1024]
    float* idx_out  = out + 2 + 4194304 + 67108864;   // [65536,1]

    unsigned int* hist = (unsigned int*)d_ws;         // [1024] u32
    float* partials    = (float*)d_ws + 1024;         // [1024] f32
    float* ee          = (float*)d_ws + 2048;         // [1024] f32

    hipMemsetAsync(d_ws, 0, 2048 * sizeof(float), stream);  // hist + partials
    k_ee<<<Kc / 256, 256, 0, stream>>>(emb, ee);
    k_main<<<65536 / 64, 256, 0, stream>>>(inputs, emb, ee, quant, enc, idx_out, hist, partials);
    k_fin<<<1, 1024, 0, stream>>>(hist, partials, loss_out, perp_out);
}